// Round 9
// baseline (278.717 us; speedup 1.0000x reference)
//
#include <hip/hip_runtime.h>
#include <hip/hip_bf16.h>

#define S_ 128
#define R_ 384
#define D_ 256
#define DP_ 128
#define H_ 8
#define HD_ 32

typedef __attribute__((ext_vector_type(8))) short short8;
typedef __attribute__((ext_vector_type(4))) float f32x4;

__device__ __forceinline__ unsigned short f2bf(float f) {
    unsigned u = __builtin_bit_cast(unsigned, f);
    u = u + 0x7FFFu + ((u >> 16) & 1u);
    return (unsigned short)(u >> 16);
}
__device__ __forceinline__ float bf2f(unsigned short h) {
    unsigned u = ((unsigned)h) << 16;
    return __builtin_bit_cast(float, u);
}
// async global->LDS, 16B per lane; dest = wave-uniform base + lane*16B
__device__ __forceinline__ void gload16(const unsigned short* g, unsigned short* l) {
    __builtin_amdgcn_global_load_lds(
        (const __attribute__((address_space(1))) unsigned int*)g,
        (__attribute__((address_space(3))) unsigned int*)l, 16, 0, 0);
}

// ---------------------------------------------------------------- weights->bf16
__global__ __launch_bounds__(256) void wconv_kernel(
    const float* __restrict__ Wq, const float* __restrict__ Wk,
    const float* __restrict__ Wv, const float* __restrict__ Wg,
    const float* __restrict__ Wo,
    unsigned short* __restrict__ wcat, unsigned short* __restrict__ wo)
{
    int i = blockIdx.x * 256 + threadIdx.x;   // grid covers 1024*256
    int rowblk = i >> 16;
    const float* src = (rowblk == 0) ? Wq : (rowblk == 1) ? Wk : (rowblk == 2) ? Wv : Wg;
    wcat[i] = f2bf(src[i & 65535]);
    if (i < 256 * 256) wo[i] = f2bf(Wo[i]);
}

// ------------------------------------------------- pair LN + bias = z_n @ Wz^T
// Layout for swapped-QK attn: C[k][q] frag. lane = ((kk%16)/4)*16 + q%16, ri = kk%4
// biasf[((h*24 + qt)*24 + ct)*256 + lane*4 + ri],  qt = q/16, ct = kk/16
__global__ __launch_bounds__(256) void bias_kernel(
    const float* __restrict__ z, const float* __restrict__ lnw,
    const float* __restrict__ lnb, const float* __restrict__ Wz,
    unsigned short* __restrict__ biasf)
{
    const int lane = threadIdx.x & 63;
    const int w = threadIdx.x >> 6;
    const int p = blockIdx.x * 4 + w;
    const int q = p / R_;
    const int kk = p - q * R_;
    const float2 zv = *(const float2*)(z + (size_t)(q * R_ + kk) * DP_ + lane * 2);
    float s1 = zv.x + zv.y;
    float s2 = zv.x * zv.x + zv.y * zv.y;
#pragma unroll
    for (int t = 32; t >= 1; t >>= 1) { s1 += __shfl_xor(s1, t); s2 += __shfl_xor(s2, t); }
    const float mu = s1 * (1.0f / DP_);
    const float rstd = rsqrtf(s2 * (1.0f / DP_) - mu * mu + 1e-5f);
    const int d0 = lane * 2;
    const float zn0 = (zv.x - mu) * rstd * lnw[d0] + lnb[d0];
    const float zn1 = (zv.y - mu) * rstd * lnw[d0 + 1] + lnb[d0 + 1];
    float res[H_];
#pragma unroll
    for (int h = 0; h < H_; h++) {
        float pa = zn0 * Wz[h * DP_ + d0] + zn1 * Wz[h * DP_ + d0 + 1];
#pragma unroll
        for (int t = 32; t >= 1; t >>= 1) pa += __shfl_xor(pa, t);
        res[h] = pa;
    }
    if (lane == 0) {
        const int qt = q >> 4, ct = kk >> 4;
        const size_t off = (size_t)((((kk & 15) >> 2) << 4) | (q & 15)) * 4 + (kk & 3);
#pragma unroll
        for (int h = 0; h < H_; h++)
            biasf[(((size_t)(h * 24 + qt) * 24 + ct) << 8) + off] = f2bf(res[h]);
    }
}

// ---------------------------------------------------------------- MSA layernorm
__global__ __launch_bounds__(256) void lnm_kernel(
    const float* __restrict__ m, const float* __restrict__ lnw,
    const float* __restrict__ lnb, unsigned short* __restrict__ mn)
{
    const int lane = threadIdx.x & 63;
    const int w = threadIdx.x >> 6;
    const size_t row = (size_t)blockIdx.x * 4 + w;
    const float4 v = *(const float4*)(m + row * D_ + lane * 4);
    float s1 = v.x + v.y + v.z + v.w;
    float s2 = v.x * v.x + v.y * v.y + v.z * v.z + v.w * v.w;
#pragma unroll
    for (int t = 32; t >= 1; t >>= 1) { s1 += __shfl_xor(s1, t); s2 += __shfl_xor(s2, t); }
    const float mu = s1 * (1.0f / D_);
    const float rstd = rsqrtf(s2 * (1.0f / D_) - mu * mu + 1e-5f);
    const int d0 = lane * 4;
    ushort4 o;
    o.x = f2bf((v.x - mu) * rstd * lnw[d0 + 0] + lnb[d0 + 0]);
    o.y = f2bf((v.y - mu) * rstd * lnw[d0 + 1] + lnb[d0 + 1]);
    o.z = f2bf((v.z - mu) * rstd * lnw[d0 + 2] + lnb[d0 + 2]);
    o.w = f2bf((v.w - mu) * rstd * lnw[d0 + 3] + lnb[d0 + 3]);
    *(ushort4*)(mn + row * D_ + d0) = o;
}

// ------------------------------------------------------------------- MFMA GEMM
// C[M x N] = X[M x 256] * W[N x 256]^T ; BM=BN=128 BK=64, 4 K-steps, 4 waves
// (2x2), wave computes 64x64 via 4x4 16x16x32 frags. global_load_lds width=16
// staging, both-sides chunk swizzle (conflict-free, R8-verified: conflicts=0).
// vt-category blocks (cat==2) compute the TRANSPOSED fragment via swapped
// mfma(B,A) so the store's lane dim lands on r (vt's contiguous axis):
// 8x16B segments per store inst instead of 64x2B scatter.
// EPI 0: N=1024, cat = by>>1 -> q(scaled)/k/vt(transposed+chunk-swizzled)/g(sigmoid)
// EPI 1: N=256 plain f32 store
template <int EPI>
__global__ __launch_bounds__(256) void gemm_kernel(
    const unsigned short* __restrict__ X, const unsigned short* __restrict__ W,
    const float* __restrict__ bg,
    unsigned short* __restrict__ outq, unsigned short* __restrict__ outk,
    unsigned short* __restrict__ outvt, unsigned short* __restrict__ outg,
    float* __restrict__ outf)
{
    __shared__ unsigned short As[128 * 64];
    __shared__ unsigned short Bs[128 * 64];
    const int tid = threadIdx.x;
    const int lane = tid & 63;
    const int w = tid >> 6;
    const int wr = w >> 1, wc = w & 1;
    const int m0 = blockIdx.x * 128;
    const int n0 = blockIdx.y * 128;
    const int rg = lane >> 4;
    const int cl = lane & 15;
    const int ca = cl & 7;
    const int lr = lane >> 3;          // row within 8-row group
    const int lc = lane & 7;           // stored chunk
    const int swc = lc ^ lr;           // source chunk (pre-swizzle)
    const bool swp = (EPI == 0) && ((blockIdx.y >> 1) == 2);
    const unsigned short* asrc = X + (size_t)(m0 + w * 32 + lr) * 256 + swc * 8;
    const unsigned short* bsrc = W + (size_t)(n0 + w * 32 + lr) * 256 + swc * 8;
    unsigned short* adst = &As[(w * 32) * 64];
    unsigned short* bdst = &Bs[(w * 32) * 64];
    f32x4 acc[4][4];
#pragma unroll
    for (int i = 0; i < 4; i++)
#pragma unroll
        for (int j = 0; j < 4; j++)
#pragma unroll
            for (int e = 0; e < 4; e++) acc[i][j][e] = 0.0f;
#pragma unroll
    for (int t = 0; t < 4; t++) {
        if (t) __syncthreads();        // all waves done reading before overwrite
        const int k0 = t * 64;
#pragma unroll
        for (int c = 0; c < 4; c++) {  // 8 rows per call, 4 calls = 32 rows/wave
            gload16(asrc + c * 8 * 256 + k0, adst + c * 512);
            gload16(bsrc + c * 8 * 256 + k0, bdst + c * 512);
        }
        asm volatile("s_waitcnt vmcnt(0)" ::: "memory");
        __syncthreads();
#pragma unroll
        for (int kk = 0; kk < 2; kk++) {
            short8 af[4], bf[4];
#pragma unroll
            for (int i = 0; i < 4; i++)
                af[i] = *(const short8*)(&As[(wr * 64 + i * 16 + cl) * 64 + (((kk * 4 + rg) ^ ca) << 3)]);
#pragma unroll
            for (int j = 0; j < 4; j++)
                bf[j] = *(const short8*)(&Bs[(wc * 64 + j * 16 + cl) * 64 + (((kk * 4 + rg) ^ ca) << 3)]);
            if (swp) {
#pragma unroll
                for (int i = 0; i < 4; i++)
#pragma unroll
                    for (int j = 0; j < 4; j++)
                        acc[i][j] = __builtin_amdgcn_mfma_f32_16x16x32_bf16(bf[j], af[i], acc[i][j], 0, 0, 0);
            } else {
#pragma unroll
                for (int i = 0; i < 4; i++)
#pragma unroll
                    for (int j = 0; j < 4; j++)
                        acc[i][j] = __builtin_amdgcn_mfma_f32_16x16x32_bf16(af[i], bf[j], acc[i][j], 0, 0, 0);
            }
        }
    }
#pragma unroll
    for (int mi = 0; mi < 4; mi++) {
        const int tilebase = m0 + wr * 64 + mi * 16;      // 16-row tile, never straddles s
        const int s = tilebase / R_;
        const int rbase = tilebase - s * R_;
        const int r0 = rbase + rg * 4;
#pragma unroll
        for (int nj = 0; nj < 4; nj++) {
            if constexpr (EPI == 0) {
                const int cat = blockIdx.y >> 1;
                if (cat == 2) {
                    // swapped fragment: lane holds C[m = tilebase+cl][n-sub = rg*4+ri]
                    const int rr = rbase + cl;
                    const int colb = ((blockIdx.y & 1) * 128) + wc * 64 + nj * 16;
#pragma unroll
                    for (int ri = 0; ri < 4; ri++) {
                        const int col = colb + rg * 4 + ri;
                        const int hh = col >> 5, jj = col & 31;
                        const int swz = (((rr >> 3) ^ (jj & 7)) << 3) | (rr & 7);
                        outvt[(((size_t)(s * H_ + hh) * HD_) + jj) * R_ + swz] = f2bf(acc[mi][nj][ri]);
                    }
                } else {
                    const int col = ((blockIdx.y & 1) * 128) + wc * 64 + nj * 16 + cl;  // 0..255
                    const int h = col >> 5, j = col & 31;
                    if (cat == 0) {
#pragma unroll
                        for (int ri = 0; ri < 4; ri++)
                            outq[(((size_t)(s * H_ + h) * R_) + r0 + ri) * HD_ + j] =
                                f2bf(acc[mi][nj][ri] * 0.17677669529663687f);
                    } else if (cat == 1) {
#pragma unroll
                        for (int ri = 0; ri < 4; ri++)
                            outk[(((size_t)(s * H_ + h) * R_) + r0 + ri) * HD_ + j] = f2bf(acc[mi][nj][ri]);
                    } else {
                        const float bgv = bg[col];
#pragma unroll
                        for (int ri = 0; ri < 4; ri++) {
                            const float sg = 1.0f / (1.0f + __expf(-(acc[mi][nj][ri] + bgv)));
                            outg[((size_t)(s * R_ + r0 + ri)) * 256 + col] = f2bf(sg);
                        }
                    }
                }
            } else {
                const int col = n0 + wc * 64 + nj * 16 + cl;
#pragma unroll
                for (int ri = 0; ri < 4; ri++)
                    outf[((size_t)(s * R_ + r0 + ri)) * 256 + col] = acc[mi][nj][ri];
            }
        }
    }
}

// ------------------------------------------------------------------- attention
// grid (s=128, h=8); 4 waves; each block owns the full (s,h): K[384][32] and
// VT[32][384] (global pre-swizzled: 16B chunk ^= row&7) staged ONCE into LDS
// via a 12-deep reg-staged burst. Each wave processes 6 q-tiles. Swapped QK^T
// (C[k][q] frag, bias+mask as C-init), no max-subtraction (|S|<=~8 by
// construction, validated R5), exp+pack fused per 32-k chunk through a tiny
// per-wave [16][40] dbuf, PV swapped (O^T = mfma(VT,P^T)), 1/sum+gate epilogue.
__global__ __launch_bounds__(256) void attn_kernel(
    const unsigned short* __restrict__ Q, const unsigned short* __restrict__ K,
    const unsigned short* __restrict__ VTX, const unsigned short* __restrict__ G,
    const unsigned short* __restrict__ biasf, const float* __restrict__ mask,
    unsigned short* __restrict__ O)
{
    __shared__ unsigned short Ks[384 * 32];        // 24 KB, row-major [k-row][32]
    __shared__ unsigned short Vs[32 * 384];        // 24 KB, [d-row][384], chunk-swizzled
    __shared__ unsigned short P[4][2][16][40];     // 10 KB, per-wave dbuf
    __shared__ float mk[R_];
    const int tid = threadIdx.x;
    const int lane = tid & 63;
    const int w = tid >> 6;
    const int s = blockIdx.x;
    const int h = blockIdx.y;
    const int rg = lane >> 4;
    const int cl = lane & 15;
    const size_t base = ((size_t)s * H_ + h) * (R_ * HD_);
    // ---- stage K + VT with one 12-deep load burst, then LDS writes ----
    short8 stg[12];
#pragma unroll
    for (int i = 0; i < 6; i++)
        stg[i] = *(const short8*)(K + base + (i * 256 + tid) * 8);
#pragma unroll
    for (int i = 0; i < 6; i++)
        stg[6 + i] = *(const short8*)(VTX + base + (i * 256 + tid) * 8);
    if (tid < 96)
        *(float4*)&mk[tid * 4] = *(const float4*)(mask + (size_t)s * R_ + tid * 4);
#pragma unroll
    for (int i = 0; i < 6; i++) *(short8*)(&Ks[(i * 256 + tid) * 8]) = stg[i];
#pragma unroll
    for (int i = 0; i < 6; i++) *(short8*)(&Vs[(i * 256 + tid) * 8]) = stg[6 + i];
    __syncthreads();
    // ---- per-wave q-tile loop ----
    for (int zz = 0; zz < 6; zz++) {
        const int qtile = zz * 4 + w;
        const int qbase = qtile * 16;
        const short8 qf = *(const short8*)(Q + base + (qbase + cl) * HD_ + rg * 8);
        const unsigned short* bp = biasf + (((size_t)(h * 24 + qtile) * 24) << 8) + (size_t)lane * 4;
        ushort4 bv[24];
#pragma unroll
        for (int ct = 0; ct < 24; ct++) bv[ct] = *(const ushort4*)(bp + ct * 256);
        float sm0 = 0.f, sm1 = 0.f, sm2 = 0.f, sm3 = 0.f;
        f32x4 oa[2][2];
#pragma unroll
        for (int i = 0; i < 2; i++)
#pragma unroll
            for (int p2 = 0; p2 < 2; p2++)
#pragma unroll
                for (int e = 0; e < 4; e++) oa[i][p2][e] = 0.0f;
#pragma unroll
        for (int t = 0; t < 12; t++) {
            // QK^T for the two 16-k halves of this 32-k chunk, fused exp+pack
#pragma unroll
            for (int half = 0; half < 2; half++) {
                const int ct = 2 * t + half;
                const short8 kf = *(const short8*)(&Ks[(ct * 16 + cl) * 32 + rg * 8]);
                const float4 m4 = *(const float4*)(&mk[ct * 16 + rg * 4]);
                f32x4 ini;
                ini[0] = bf2f(bv[ct].x) + m4.x;
                ini[1] = bf2f(bv[ct].y) + m4.y;
                ini[2] = bf2f(bv[ct].z) + m4.z;
                ini[3] = bf2f(bv[ct].w) + m4.w;
                const f32x4 sv = __builtin_amdgcn_mfma_f32_16x16x32_bf16(kf, qf, ini, 0, 0, 0);
                const float e0 = __expf(sv[0]);
                const float e1 = __expf(sv[1]);
                const float e2 = __expf(sv[2]);
                const float e3 = __expf(sv[3]);
                sm0 += e0; sm1 += e1; sm2 += e2; sm3 += e3;
                uint2 pk;
                pk.x = (unsigned)f2bf(e0) | ((unsigned)f2bf(e1) << 16);
                pk.y = (unsigned)f2bf(e2) | ((unsigned)f2bf(e3) << 16);
                *(uint2*)(&P[w][t & 1][cl][half * 16 + rg * 4]) = pk;
            }
            // same-wave LDS write->read fence
            asm volatile("s_waitcnt lgkmcnt(0)" ::: "memory");
            const short8 pf = *(const short8*)(&P[w][t & 1][cl][rg * 8]);
#pragma unroll
            for (int sub = 0; sub < 2; sub++) {
                const int row = sub * 16 + cl;
                const short8 vf = *(const short8*)(&Vs[row * 384 + (((t * 4 + rg) ^ (row & 7)) << 3)]);
                oa[sub][t & 1] = __builtin_amdgcn_mfma_f32_16x16x32_bf16(vf, pf, oa[sub][t & 1], 0, 0, 0);
            }
        }
        float sum = (sm0 + sm1) + (sm2 + sm3);
        sum += __shfl_xor(sum, 16);
        sum += __shfl_xor(sum, 32);
        const float inv = 1.0f / sum;
        // epilogue: normalize, gate, store. lane holds O^T[d=sub*16+rg*4+ri][q=qbase+cl]
        const size_t orow = (size_t)(s * R_ + qbase + cl) * 256 + h * HD_;
#pragma unroll
        for (int sub = 0; sub < 2; sub++) {
            const ushort4 gv = *(const ushort4*)(G + orow + sub * 16 + rg * 4);
            ushort4 ov;
            ov.x = f2bf((oa[sub][0][0] + oa[sub][1][0]) * inv * bf2f(gv.x));
            ov.y = f2bf((oa[sub][0][1] + oa[sub][1][1]) * inv * bf2f(gv.y));
            ov.z = f2bf((oa[sub][0][2] + oa[sub][1][2]) * inv * bf2f(gv.z));
            ov.w = f2bf((oa[sub][0][3] + oa[sub][1][3]) * inv * bf2f(gv.w));
            *(ushort4*)(O + orow + sub * 16 + rg * 4) = ov;
        }
    }
}

// ------------------------------------------------------------------------ host
extern "C" void kernel_launch(void* const* d_in, const int* in_sizes, int n_in,
                              void* d_out, int out_size, void* d_ws, size_t ws_size,
                              hipStream_t stream)
{
    const float* m      = (const float*)d_in[0];
    const float* z      = (const float*)d_in[1];
    const float* mask   = (const float*)d_in[2];
    const float* ln_m_w = (const float*)d_in[3];
    const float* ln_m_b = (const float*)d_in[4];
    const float* ln_z_w = (const float*)d_in[5];
    const float* ln_z_b = (const float*)d_in[6];
    const float* Wz     = (const float*)d_in[7];
    const float* Wq     = (const float*)d_in[8];
    const float* Wk     = (const float*)d_in[9];
    const float* Wv     = (const float*)d_in[10];
    const float* Wg     = (const float*)d_in[11];
    const float* bg     = (const float*)d_in[12];
    const float* Wo     = (const float*)d_in[13];
    float* out = (float*)d_out;
    char* ws = (char*)d_ws;

    // ws layout (bytes)
    unsigned short* wbias = (unsigned short*)(ws);                         //  2,359,296
    unsigned short* wmn   = (unsigned short*)(ws + 2359296);               // 25,165,824 (reused as attn O)
    unsigned short* wq    = (unsigned short*)(ws + 27525120);              // 25,165,824
    unsigned short* wk    = (unsigned short*)(ws + 52690944);              // 25,165,824
    unsigned short* wvt   = (unsigned short*)(ws + 77856768);              // 25,165,824
    unsigned short* wg    = (unsigned short*)(ws + 103022592);             // 25,165,824
    unsigned short* wcat  = (unsigned short*)(ws + 128188416);             //    524,288
    unsigned short* wwo   = (unsigned short*)(ws + 128712704);             //    131,072

    wconv_kernel<<<1024, 256, 0, stream>>>(Wq, Wk, Wv, Wg, Wo, wcat, wwo);
    bias_kernel<<<36864, 256, 0, stream>>>(z, ln_z_w, ln_z_b, Wz, wbias);
    lnm_kernel<<<12288, 256, 0, stream>>>(m, ln_m_w, ln_m_b, wmn);
    gemm_kernel<0><<<dim3(384, 8), 256, 0, stream>>>(wmn, wcat, bg, wq, wk, wvt, wg, nullptr);
    attn_kernel<<<dim3(128, 8), 256, 0, stream>>>(wq, wk, wvt, wg, wbias, mask, wmn);
    gemm_kernel<1><<<dim3(384, 2), 256, 0, stream>>>(wmn, wwo, nullptr, nullptr, nullptr, nullptr, nullptr, out);
}

// Round 10
// 261.050 us; speedup vs baseline: 1.0677x; 1.0677x over previous
//
#include <hip/hip_runtime.h>
#include <hip/hip_bf16.h>

#define S_ 128
#define R_ 384
#define D_ 256
#define DP_ 128
#define H_ 8
#define HD_ 32

typedef __attribute__((ext_vector_type(8))) short short8;
typedef __attribute__((ext_vector_type(4))) float f32x4;

__device__ __forceinline__ unsigned short f2bf(float f) {
    unsigned u = __builtin_bit_cast(unsigned, f);
    u = u + 0x7FFFu + ((u >> 16) & 1u);
    return (unsigned short)(u >> 16);
}
__device__ __forceinline__ float bf2f(unsigned short h) {
    unsigned u = ((unsigned)h) << 16;
    return __builtin_bit_cast(float, u);
}
// async global->LDS, 16B per lane; dest = wave-uniform base + lane*16B
__device__ __forceinline__ void gload16(const unsigned short* g, unsigned short* l) {
    __builtin_amdgcn_global_load_lds(
        (const __attribute__((address_space(1))) unsigned int*)g,
        (__attribute__((address_space(3))) unsigned int*)l, 16, 0, 0);
}

// ---------------------------------------------------------------- weights->bf16
__global__ __launch_bounds__(256) void wconv_kernel(
    const float* __restrict__ Wq, const float* __restrict__ Wk,
    const float* __restrict__ Wv, const float* __restrict__ Wg,
    const float* __restrict__ Wo,
    unsigned short* __restrict__ wcat, unsigned short* __restrict__ wo)
{
    int i = blockIdx.x * 256 + threadIdx.x;   // grid covers 1024*256
    int rowblk = i >> 16;
    const float* src = (rowblk == 0) ? Wq : (rowblk == 1) ? Wk : (rowblk == 2) ? Wv : Wg;
    wcat[i] = f2bf(src[i & 65535]);
    if (i < 256 * 256) wo[i] = f2bf(Wo[i]);
}

// ------------------------------------------------- pair LN + bias = z_n @ Wz^T
// Layout for swapped-QK attn: C[k][q] frag. lane = ((kk%16)/4)*16 + q%16, ri = kk%4
// biasf[((h*24 + qt)*24 + ct)*256 + lane*4 + ri],  qt = q/16, ct = kk/16
__global__ __launch_bounds__(256) void bias_kernel(
    const float* __restrict__ z, const float* __restrict__ lnw,
    const float* __restrict__ lnb, const float* __restrict__ Wz,
    unsigned short* __restrict__ biasf)
{
    const int lane = threadIdx.x & 63;
    const int w = threadIdx.x >> 6;
    const int p = blockIdx.x * 4 + w;
    const int q = p / R_;
    const int kk = p - q * R_;
    const float2 zv = *(const float2*)(z + (size_t)(q * R_ + kk) * DP_ + lane * 2);
    float s1 = zv.x + zv.y;
    float s2 = zv.x * zv.x + zv.y * zv.y;
#pragma unroll
    for (int t = 32; t >= 1; t >>= 1) { s1 += __shfl_xor(s1, t); s2 += __shfl_xor(s2, t); }
    const float mu = s1 * (1.0f / DP_);
    const float rstd = rsqrtf(s2 * (1.0f / DP_) - mu * mu + 1e-5f);
    const int d0 = lane * 2;
    const float zn0 = (zv.x - mu) * rstd * lnw[d0] + lnb[d0];
    const float zn1 = (zv.y - mu) * rstd * lnw[d0 + 1] + lnb[d0 + 1];
    float res[H_];
#pragma unroll
    for (int h = 0; h < H_; h++) {
        float pa = zn0 * Wz[h * DP_ + d0] + zn1 * Wz[h * DP_ + d0 + 1];
#pragma unroll
        for (int t = 32; t >= 1; t >>= 1) pa += __shfl_xor(pa, t);
        res[h] = pa;
    }
    if (lane == 0) {
        const int qt = q >> 4, ct = kk >> 4;
        const size_t off = (size_t)((((kk & 15) >> 2) << 4) | (q & 15)) * 4 + (kk & 3);
#pragma unroll
        for (int h = 0; h < H_; h++)
            biasf[(((size_t)(h * 24 + qt) * 24 + ct) << 8) + off] = f2bf(res[h]);
    }
}

// ---------------------------------------------------------------- MSA layernorm
__global__ __launch_bounds__(256) void lnm_kernel(
    const float* __restrict__ m, const float* __restrict__ lnw,
    const float* __restrict__ lnb, unsigned short* __restrict__ mn)
{
    const int lane = threadIdx.x & 63;
    const int w = threadIdx.x >> 6;
    const size_t row = (size_t)blockIdx.x * 4 + w;
    const float4 v = *(const float4*)(m + row * D_ + lane * 4);
    float s1 = v.x + v.y + v.z + v.w;
    float s2 = v.x * v.x + v.y * v.y + v.z * v.z + v.w * v.w;
#pragma unroll
    for (int t = 32; t >= 1; t >>= 1) { s1 += __shfl_xor(s1, t); s2 += __shfl_xor(s2, t); }
    const float mu = s1 * (1.0f / D_);
    const float rstd = rsqrtf(s2 * (1.0f / D_) - mu * mu + 1e-5f);
    const int d0 = lane * 4;
    ushort4 o;
    o.x = f2bf((v.x - mu) * rstd * lnw[d0 + 0] + lnb[d0 + 0]);
    o.y = f2bf((v.y - mu) * rstd * lnw[d0 + 1] + lnb[d0 + 1]);
    o.z = f2bf((v.z - mu) * rstd * lnw[d0 + 2] + lnb[d0 + 2]);
    o.w = f2bf((v.w - mu) * rstd * lnw[d0 + 3] + lnb[d0 + 3]);
    *(ushort4*)(mn + row * D_ + d0) = o;
}

// ------------------------------------------------------------------- MFMA GEMM
// C[M x N] = X[M x 256] * W[N x 256]^T ; BM=128 BN=64 BK=128, 2 K-steps,
// 8 waves (4x2), wave computes 32x32 via 2x2 16x16x32 frags (16 acc regs ->
// high occupancy: LDS 48KB caps at 3 blocks = 24 waves/CU).
// Staging: global_load_lds width=16, linear LDS, both-sides chunk swizzle
// (16B slots: stored slot = chunk ^ (row&7); conflict-free, R8-verified).
// EPI 0: N=1024, cat = by>>2 -> q(scaled)/k/vt(transposed+chunk-swizzled)/g(sigmoid)
// EPI 1: N=256 plain f32 store
template <int EPI>
__global__ __launch_bounds__(512) void gemm_kernel(
    const unsigned short* __restrict__ X, const unsigned short* __restrict__ W,
    const float* __restrict__ bg,
    unsigned short* __restrict__ outq, unsigned short* __restrict__ outk,
    unsigned short* __restrict__ outvt, unsigned short* __restrict__ outg,
    float* __restrict__ outf)
{
    __shared__ unsigned short As[128 * 128];
    __shared__ unsigned short Bs[64 * 128];
    const int tid = threadIdx.x;
    const int lane = tid & 63;
    const int w = tid >> 6;            // 0..7
    const int wr = w >> 1, wc = w & 1; // 4 x 2 wave grid
    const int m0 = blockIdx.x * 128;
    const int n0 = blockIdx.y * 64;
    const int rg = lane >> 4;          // 0..3 (also row-in-call for staging)
    const int cl = lane & 15;          // 0..15 (also dest slot for staging)
    const int ca = cl & 7;
    f32x4 acc[2][2];
#pragma unroll
    for (int i = 0; i < 2; i++)
#pragma unroll
        for (int j = 0; j < 2; j++)
#pragma unroll
            for (int e = 0; e < 4; e++) acc[i][j][e] = 0.0f;
#pragma unroll
    for (int t = 0; t < 2; t++) {
        if (t) __syncthreads();        // all waves done reading before overwrite
        const int k0 = t * 128;
#pragma unroll
        for (int c = 0; c < 4; c++) {  // A: wave stages rows w*16 .. w*16+15
            const int row = w * 16 + c * 4 + rg;
            gload16(X + (size_t)(m0 + row) * 256 + k0 + ((cl ^ (row & 7)) << 3),
                    &As[(w * 16 + c * 4) * 128]);
        }
#pragma unroll
        for (int c = 0; c < 2; c++) {  // B: wave stages rows w*8 .. w*8+7
            const int row = w * 8 + c * 4 + rg;
            gload16(W + (size_t)(n0 + row) * 256 + k0 + ((cl ^ (row & 7)) << 3),
                    &Bs[(w * 8 + c * 4) * 128]);
        }
        asm volatile("s_waitcnt vmcnt(0)" ::: "memory");
        __syncthreads();
#pragma unroll
        for (int kk = 0; kk < 4; kk++) {
            short8 af[2], bf[2];
#pragma unroll
            for (int i = 0; i < 2; i++)
                af[i] = *(const short8*)(&As[(wr * 32 + i * 16 + cl) * 128 + (((kk * 4 + rg) ^ ca) << 3)]);
#pragma unroll
            for (int j = 0; j < 2; j++)
                bf[j] = *(const short8*)(&Bs[(wc * 32 + j * 16 + cl) * 128 + (((kk * 4 + rg) ^ ca) << 3)]);
#pragma unroll
            for (int i = 0; i < 2; i++)
#pragma unroll
                for (int j = 0; j < 2; j++)
                    acc[i][j] = __builtin_amdgcn_mfma_f32_16x16x32_bf16(af[i], bf[j], acc[i][j], 0, 0, 0);
        }
    }
#pragma unroll
    for (int mi = 0; mi < 2; mi++) {
        const int tilebase = m0 + wr * 32 + mi * 16;      // 16-row tile, never straddles s
        const int s = tilebase / R_;
        const int r0 = tilebase - s * R_ + rg * 4;
#pragma unroll
        for (int nj = 0; nj < 2; nj++) {
            if constexpr (EPI == 0) {
                const int cat = blockIdx.y >> 2;
                const int col = ((blockIdx.y & 3) * 64) + wc * 32 + nj * 16 + cl;  // 0..255
                const int h = col >> 5, j = col & 31;
                if (cat == 0) {
#pragma unroll
                    for (int ri = 0; ri < 4; ri++)
                        outq[(((size_t)(s * H_ + h) * R_) + r0 + ri) * HD_ + j] =
                            f2bf(acc[mi][nj][ri] * 0.17677669529663687f);
                } else if (cat == 1) {
#pragma unroll
                    for (int ri = 0; ri < 4; ri++)
                        outk[(((size_t)(s * H_ + h) * R_) + r0 + ri) * HD_ + j] = f2bf(acc[mi][nj][ri]);
                } else if (cat == 2) {
#pragma unroll
                    for (int ri = 0; ri < 4; ri++) {
                        const int r = r0 + ri;
                        const int swz = ((((r >> 3) ^ (j & 7)) << 3) | (r & 7));
                        outvt[(((size_t)(s * H_ + h) * HD_) + j) * R_ + swz] = f2bf(acc[mi][nj][ri]);
                    }
                } else {
                    const float bgv = bg[col];
#pragma unroll
                    for (int ri = 0; ri < 4; ri++) {
                        const float sg = 1.0f / (1.0f + __expf(-(acc[mi][nj][ri] + bgv)));
                        outg[((size_t)(s * R_ + r0 + ri)) * 256 + col] = f2bf(sg);
                    }
                }
            } else {
                const int col = n0 + wc * 32 + nj * 16 + cl;
#pragma unroll
                for (int ri = 0; ri < 4; ri++)
                    outf[((size_t)(s * R_ + r0 + ri)) * 256 + col] = acc[mi][nj][ri];
            }
        }
    }
}

// ------------------------------------------------------------------- attention
// grid (s=128, h=8); 4 waves; each block owns the full (s,h): K[384][32] and
// VT[32][384] (global pre-swizzled: 16B chunk ^= row&7) staged ONCE into LDS
// via a 12-deep reg-staged burst. Each wave processes 6 q-tiles. Swapped QK^T
// (C[k][q] frag, bias+mask as C-init), no max-subtraction (|S|<=~8 by
// construction, validated R5), exp+pack fused per 32-k chunk through a tiny
// per-wave [16][40] dbuf, PV swapped (O^T = mfma(VT,P^T)), 1/sum+gate epilogue.
__global__ __launch_bounds__(256) void attn_kernel(
    const unsigned short* __restrict__ Q, const unsigned short* __restrict__ K,
    const unsigned short* __restrict__ VTX, const unsigned short* __restrict__ G,
    const unsigned short* __restrict__ biasf, const float* __restrict__ mask,
    unsigned short* __restrict__ O)
{
    __shared__ unsigned short Ks[384 * 32];        // 24 KB, row-major [k-row][32]
    __shared__ unsigned short Vs[32 * 384];        // 24 KB, [d-row][384], chunk-swizzled
    __shared__ unsigned short P[4][2][16][40];     // 10 KB, per-wave dbuf
    __shared__ float mk[R_];
    const int tid = threadIdx.x;
    const int lane = tid & 63;
    const int w = tid >> 6;
    const int s = blockIdx.x;
    const int h = blockIdx.y;
    const int rg = lane >> 4;
    const int cl = lane & 15;
    const size_t base = ((size_t)s * H_ + h) * (R_ * HD_);
    // ---- stage K + VT with one 12-deep load burst, then LDS writes ----
    short8 stg[12];
#pragma unroll
    for (int i = 0; i < 6; i++)
        stg[i] = *(const short8*)(K + base + (i * 256 + tid) * 8);
#pragma unroll
    for (int i = 0; i < 6; i++)
        stg[6 + i] = *(const short8*)(VTX + base + (i * 256 + tid) * 8);
    if (tid < 96)
        *(float4*)&mk[tid * 4] = *(const float4*)(mask + (size_t)s * R_ + tid * 4);
#pragma unroll
    for (int i = 0; i < 6; i++) *(short8*)(&Ks[(i * 256 + tid) * 8]) = stg[i];
#pragma unroll
    for (int i = 0; i < 6; i++) *(short8*)(&Vs[(i * 256 + tid) * 8]) = stg[6 + i];
    __syncthreads();
    // ---- per-wave q-tile loop ----
    for (int zz = 0; zz < 6; zz++) {
        const int qtile = zz * 4 + w;
        const int qbase = qtile * 16;
        const short8 qf = *(const short8*)(Q + base + (qbase + cl) * HD_ + rg * 8);
        const unsigned short* bp = biasf + (((size_t)(h * 24 + qtile) * 24) << 8) + (size_t)lane * 4;
        ushort4 bv[24];
#pragma unroll
        for (int ct = 0; ct < 24; ct++) bv[ct] = *(const ushort4*)(bp + ct * 256);
        float sm0 = 0.f, sm1 = 0.f, sm2 = 0.f, sm3 = 0.f;
        f32x4 oa[2][2];
#pragma unroll
        for (int i = 0; i < 2; i++)
#pragma unroll
            for (int p2 = 0; p2 < 2; p2++)
#pragma unroll
                for (int e = 0; e < 4; e++) oa[i][p2][e] = 0.0f;
#pragma unroll
        for (int t = 0; t < 12; t++) {
            // QK^T for the two 16-k halves of this 32-k chunk, fused exp+pack
#pragma unroll
            for (int half = 0; half < 2; half++) {
                const int ct = 2 * t + half;
                const short8 kf = *(const short8*)(&Ks[(ct * 16 + cl) * 32 + rg * 8]);
                const float4 m4 = *(const float4*)(&mk[ct * 16 + rg * 4]);
                f32x4 ini;
                ini[0] = bf2f(bv[ct].x) + m4.x;
                ini[1] = bf2f(bv[ct].y) + m4.y;
                ini[2] = bf2f(bv[ct].z) + m4.z;
                ini[3] = bf2f(bv[ct].w) + m4.w;
                const f32x4 sv = __builtin_amdgcn_mfma_f32_16x16x32_bf16(kf, qf, ini, 0, 0, 0);
                const float e0 = __expf(sv[0]);
                const float e1 = __expf(sv[1]);
                const float e2 = __expf(sv[2]);
                const float e3 = __expf(sv[3]);
                sm0 += e0; sm1 += e1; sm2 += e2; sm3 += e3;
                uint2 pk;
                pk.x = (unsigned)f2bf(e0) | ((unsigned)f2bf(e1) << 16);
                pk.y = (unsigned)f2bf(e2) | ((unsigned)f2bf(e3) << 16);
                *(uint2*)(&P[w][t & 1][cl][half * 16 + rg * 4]) = pk;
            }
            // same-wave LDS write->read fence
            asm volatile("s_waitcnt lgkmcnt(0)" ::: "memory");
            const short8 pf = *(const short8*)(&P[w][t & 1][cl][rg * 8]);
#pragma unroll
            for (int sub = 0; sub < 2; sub++) {
                const int row = sub * 16 + cl;
                const short8 vf = *(const short8*)(&Vs[row * 384 + (((t * 4 + rg) ^ (row & 7)) << 3)]);
                oa[sub][t & 1] = __builtin_amdgcn_mfma_f32_16x16x32_bf16(vf, pf, oa[sub][t & 1], 0, 0, 0);
            }
        }
        float sum = (sm0 + sm1) + (sm2 + sm3);
        sum += __shfl_xor(sum, 16);
        sum += __shfl_xor(sum, 32);
        const float inv = 1.0f / sum;
        // epilogue: normalize, gate, store. lane holds O^T[d=sub*16+rg*4+ri][q=qbase+cl]
        const size_t orow = (size_t)(s * R_ + qbase + cl) * 256 + h * HD_;
#pragma unroll
        for (int sub = 0; sub < 2; sub++) {
            const ushort4 gv = *(const ushort4*)(G + orow + sub * 16 + rg * 4);
            ushort4 ov;
            ov.x = f2bf((oa[sub][0][0] + oa[sub][1][0]) * inv * bf2f(gv.x));
            ov.y = f2bf((oa[sub][0][1] + oa[sub][1][1]) * inv * bf2f(gv.y));
            ov.z = f2bf((oa[sub][0][2] + oa[sub][1][2]) * inv * bf2f(gv.z));
            ov.w = f2bf((oa[sub][0][3] + oa[sub][1][3]) * inv * bf2f(gv.w));
            *(ushort4*)(O + orow + sub * 16 + rg * 4) = ov;
        }
    }
}

// ------------------------------------------------------------------------ host
extern "C" void kernel_launch(void* const* d_in, const int* in_sizes, int n_in,
                              void* d_out, int out_size, void* d_ws, size_t ws_size,
                              hipStream_t stream)
{
    const float* m      = (const float*)d_in[0];
    const float* z      = (const float*)d_in[1];
    const float* mask   = (const float*)d_in[2];
    const float* ln_m_w = (const float*)d_in[3];
    const float* ln_m_b = (const float*)d_in[4];
    const float* ln_z_w = (const float*)d_in[5];
    const float* ln_z_b = (const float*)d_in[6];
    const float* Wz     = (const float*)d_in[7];
    const float* Wq     = (const float*)d_in[8];
    const float* Wk     = (const float*)d_in[9];
    const float* Wv     = (const float*)d_in[10];
    const float* Wg     = (const float*)d_in[11];
    const float* bg     = (const float*)d_in[12];
    const float* Wo     = (const float*)d_in[13];
    float* out = (float*)d_out;
    char* ws = (char*)d_ws;

    // ws layout (bytes)
    unsigned short* wbias = (unsigned short*)(ws);                         //  2,359,296
    unsigned short* wmn   = (unsigned short*)(ws + 2359296);               // 25,165,824 (reused as attn O)
    unsigned short* wq    = (unsigned short*)(ws + 27525120);              // 25,165,824
    unsigned short* wk    = (unsigned short*)(ws + 52690944);              // 25,165,824
    unsigned short* wvt   = (unsigned short*)(ws + 77856768);              // 25,165,824
    unsigned short* wg    = (unsigned short*)(ws + 103022592);             // 25,165,824
    unsigned short* wcat  = (unsigned short*)(ws + 128188416);             //    524,288
    unsigned short* wwo   = (unsigned short*)(ws + 128712704);             //    131,072

    wconv_kernel<<<1024, 256, 0, stream>>>(Wq, Wk, Wv, Wg, Wo, wcat, wwo);
    bias_kernel<<<36864, 256, 0, stream>>>(z, ln_z_w, ln_z_b, Wz, wbias);
    lnm_kernel<<<12288, 256, 0, stream>>>(m, ln_m_w, ln_m_b, wmn);
    gemm_kernel<0><<<dim3(384, 16), 512, 0, stream>>>(wmn, wcat, bg, wq, wk, wvt, wg, nullptr);
    attn_kernel<<<dim3(128, 8), 256, 0, stream>>>(wq, wk, wvt, wg, wbias, mask, wmn);
    gemm_kernel<1><<<dim3(384, 4), 512, 0, stream>>>(wmn, wwo, nullptr, nullptr, nullptr, nullptr, nullptr, out);
}

// Round 11
// 212.912 us; speedup vs baseline: 1.3091x; 1.2261x over previous
//
#include <hip/hip_runtime.h>
#include <hip/hip_bf16.h>

#define S_ 128
#define R_ 384
#define D_ 256
#define DP_ 128
#define H_ 8
#define HD_ 32

typedef __attribute__((ext_vector_type(8))) short short8;
typedef __attribute__((ext_vector_type(4))) float f32x4;

__device__ __forceinline__ unsigned short f2bf(float f) {
    unsigned u = __builtin_bit_cast(unsigned, f);
    u = u + 0x7FFFu + ((u >> 16) & 1u);
    return (unsigned short)(u >> 16);
}
__device__ __forceinline__ float bf2f(unsigned short h) {
    unsigned u = ((unsigned)h) << 16;
    return __builtin_bit_cast(float, u);
}
// async global->LDS, 16B per lane; dest = wave-uniform base + lane*16B
__device__ __forceinline__ void gload16(const unsigned short* g, unsigned short* l) {
    __builtin_amdgcn_global_load_lds(
        (const __attribute__((address_space(1))) unsigned int*)g,
        (__attribute__((address_space(3))) unsigned int*)l, 16, 0, 0);
}

// ---------------------------------------------------------------- weights->bf16
__global__ __launch_bounds__(256) void wconv_kernel(
    const float* __restrict__ Wq, const float* __restrict__ Wk,
    const float* __restrict__ Wv, const float* __restrict__ Wg,
    const float* __restrict__ Wo,
    unsigned short* __restrict__ wcat, unsigned short* __restrict__ wo)
{
    int i = blockIdx.x * 256 + threadIdx.x;   // grid covers 1024*256
    int rowblk = i >> 16;
    const float* src = (rowblk == 0) ? Wq : (rowblk == 1) ? Wk : (rowblk == 2) ? Wv : Wg;
    wcat[i] = f2bf(src[i & 65535]);
    if (i < 256 * 256) wo[i] = f2bf(Wo[i]);
}

// ------------------------------------------------- bias precompute (one block)
// A[h][d] = ln_z_w[d]*Wz[h][d];  c12[h] = sum_d A[h][d];  c12[8+h] = sum_d ln_z_b[d]*Wz[h][d]
__global__ __launch_bounds__(128) void prep_kernel(
    const float* __restrict__ lnw, const float* __restrict__ lnb,
    const float* __restrict__ Wz, float* __restrict__ A, float* __restrict__ c12)
{
    __shared__ float r1[2][8], r2[2][8];
    const int d = threadIdx.x;           // 0..127
    const int wv = d >> 6, ln = d & 63;
    const float lw = lnw[d], lb = lnb[d];
    float p1[8], p2[8];
#pragma unroll
    for (int h = 0; h < 8; h++) {
        const float wz = Wz[h * DP_ + d];
        const float a = lw * wz;
        A[h * DP_ + d] = a;
        p1[h] = a;
        p2[h] = lb * wz;
    }
#pragma unroll
    for (int h = 0; h < 8; h++) {
#pragma unroll
        for (int t = 32; t >= 1; t >>= 1) {
            p1[h] += __shfl_xor(p1[h], t);
            p2[h] += __shfl_xor(p2[h], t);
        }
    }
    if (ln == 0) {
#pragma unroll
        for (int h = 0; h < 8; h++) { r1[wv][h] = p1[h]; r2[wv][h] = p2[h]; }
    }
    __syncthreads();
    if (d < 8) {
        c12[d] = r1[0][d] + r1[1][d];
        c12[8 + d] = r2[0][d] + r2[1][d];
    }
}

// ------------------------------------------------- pair LN + bias = z_n @ Wz^T
// bias[p,h] = rstd*(z.A[h]) - rstd*mu*c1[h] + c2[h]  (exact algebra, f32).
// 8 lanes per row (16 contiguous f32 each), 8 rows per wave: ONE reduction
// phase of 10 values x 3 shfl (vs 60 shfl/row before). Lane l8 stores head l8.
// Output layout (validated R5-R10): C[k][q] frag for swapped-QK attn.
__global__ __launch_bounds__(256) void bias_kernel(
    const float* __restrict__ z, const float* __restrict__ A,
    const float* __restrict__ c12, unsigned short* __restrict__ biasf)
{
    const int lane = threadIdx.x & 63;
    const int w = threadIdx.x >> 6;
    const int g = lane >> 3;
    const int l8 = lane & 7;
    const int p = blockIdx.x * 32 + w * 8 + g;
    const int q = p / R_;
    const int kk = p - q * R_;
    const float* zp = z + (size_t)p * DP_ + l8 * 16;
    const float* Ap = A + l8 * 16;
    float s1 = 0.f, s2 = 0.f;
    float d0 = 0.f, d1 = 0.f, d2 = 0.f, d3 = 0.f, d4 = 0.f, d5 = 0.f, d6 = 0.f, d7 = 0.f;
#pragma unroll
    for (int c = 0; c < 4; c++) {
        const float4 zv = *(const float4*)(zp + c * 4);
        s1 += zv.x + zv.y + zv.z + zv.w;
        s2 += zv.x * zv.x + zv.y * zv.y + zv.z * zv.z + zv.w * zv.w;
        const float4 a0 = *(const float4*)(Ap + 0 * DP_ + c * 4);
        const float4 a1 = *(const float4*)(Ap + 1 * DP_ + c * 4);
        const float4 a2 = *(const float4*)(Ap + 2 * DP_ + c * 4);
        const float4 a3 = *(const float4*)(Ap + 3 * DP_ + c * 4);
        const float4 a4 = *(const float4*)(Ap + 4 * DP_ + c * 4);
        const float4 a5 = *(const float4*)(Ap + 5 * DP_ + c * 4);
        const float4 a6 = *(const float4*)(Ap + 6 * DP_ + c * 4);
        const float4 a7 = *(const float4*)(Ap + 7 * DP_ + c * 4);
        d0 += zv.x * a0.x + zv.y * a0.y + zv.z * a0.z + zv.w * a0.w;
        d1 += zv.x * a1.x + zv.y * a1.y + zv.z * a1.z + zv.w * a1.w;
        d2 += zv.x * a2.x + zv.y * a2.y + zv.z * a2.z + zv.w * a2.w;
        d3 += zv.x * a3.x + zv.y * a3.y + zv.z * a3.z + zv.w * a3.w;
        d4 += zv.x * a4.x + zv.y * a4.y + zv.z * a4.z + zv.w * a4.w;
        d5 += zv.x * a5.x + zv.y * a5.y + zv.z * a5.z + zv.w * a5.w;
        d6 += zv.x * a6.x + zv.y * a6.y + zv.z * a6.z + zv.w * a6.w;
        d7 += zv.x * a7.x + zv.y * a7.y + zv.z * a7.z + zv.w * a7.w;
    }
#pragma unroll
    for (int t = 4; t >= 1; t >>= 1) {
        s1 += __shfl_xor(s1, t);
        s2 += __shfl_xor(s2, t);
        d0 += __shfl_xor(d0, t);
        d1 += __shfl_xor(d1, t);
        d2 += __shfl_xor(d2, t);
        d3 += __shfl_xor(d3, t);
        d4 += __shfl_xor(d4, t);
        d5 += __shfl_xor(d5, t);
        d6 += __shfl_xor(d6, t);
        d7 += __shfl_xor(d7, t);
    }
    const float mu = s1 * (1.0f / DP_);
    const float rstd = rsqrtf(s2 * (1.0f / DP_) - mu * mu + 1e-5f);
    const int h = l8;
    const float dh = (h == 0) ? d0 : (h == 1) ? d1 : (h == 2) ? d2 : (h == 3) ? d3
                   : (h == 4) ? d4 : (h == 5) ? d5 : (h == 6) ? d6 : d7;
    const float val = rstd * dh - rstd * mu * c12[h] + c12[8 + h];
    const int qt = q >> 4, ct = kk >> 4;
    const size_t off = (size_t)((((kk & 15) >> 2) << 4) | (q & 15)) * 4 + (kk & 3);
    biasf[(((size_t)(h * 24 + qt) * 24 + ct) << 8) + off] = f2bf(val);
}

// ---------------------------------------------------------------- MSA layernorm
__global__ __launch_bounds__(256) void lnm_kernel(
    const float* __restrict__ m, const float* __restrict__ lnw,
    const float* __restrict__ lnb, unsigned short* __restrict__ mn)
{
    const int lane = threadIdx.x & 63;
    const int w = threadIdx.x >> 6;
    const size_t row = (size_t)blockIdx.x * 4 + w;
    const float4 v = *(const float4*)(m + row * D_ + lane * 4);
    float s1 = v.x + v.y + v.z + v.w;
    float s2 = v.x * v.x + v.y * v.y + v.z * v.z + v.w * v.w;
#pragma unroll
    for (int t = 32; t >= 1; t >>= 1) { s1 += __shfl_xor(s1, t); s2 += __shfl_xor(s2, t); }
    const float mu = s1 * (1.0f / D_);
    const float rstd = rsqrtf(s2 * (1.0f / D_) - mu * mu + 1e-5f);
    const int d0 = lane * 4;
    ushort4 o;
    o.x = f2bf((v.x - mu) * rstd * lnw[d0 + 0] + lnb[d0 + 0]);
    o.y = f2bf((v.y - mu) * rstd * lnw[d0 + 1] + lnb[d0 + 1]);
    o.z = f2bf((v.z - mu) * rstd * lnw[d0 + 2] + lnb[d0 + 2]);
    o.w = f2bf((v.w - mu) * rstd * lnw[d0 + 3] + lnb[d0 + 3]);
    *(ushort4*)(mn + row * D_ + d0) = o;
}

// ------------------------------------------------------------------- MFMA GEMM
// C[M x N] = X[M x 256] * W[N x 256]^T ; BM=128 BN=64 BK=128, 2 K-steps,
// 8 waves (4x2), wave computes 32x32 via 2x2 16x16x32 frags (16 acc regs ->
// high occupancy: LDS 48KB caps at 3 blocks = 24 waves/CU).
// Staging: global_load_lds width=16, linear LDS, both-sides chunk swizzle
// (16B slots: stored slot = chunk ^ (row&7); conflict-free, R8-verified).
// EPI 0: N=1024, cat = by>>2 -> q(scaled)/k/vt(transposed+chunk-swizzled)/g(sigmoid)
// EPI 1: N=256 plain f32 store
template <int EPI>
__global__ __launch_bounds__(512) void gemm_kernel(
    const unsigned short* __restrict__ X, const unsigned short* __restrict__ W,
    const float* __restrict__ bg,
    unsigned short* __restrict__ outq, unsigned short* __restrict__ outk,
    unsigned short* __restrict__ outvt, unsigned short* __restrict__ outg,
    float* __restrict__ outf)
{
    __shared__ unsigned short As[128 * 128];
    __shared__ unsigned short Bs[64 * 128];
    const int tid = threadIdx.x;
    const int lane = tid & 63;
    const int w = tid >> 6;            // 0..7
    const int wr = w >> 1, wc = w & 1; // 4 x 2 wave grid
    const int m0 = blockIdx.x * 128;
    const int n0 = blockIdx.y * 64;
    const int rg = lane >> 4;          // 0..3 (also row-in-call for staging)
    const int cl = lane & 15;          // 0..15 (also dest slot for staging)
    const int ca = cl & 7;
    f32x4 acc[2][2];
#pragma unroll
    for (int i = 0; i < 2; i++)
#pragma unroll
        for (int j = 0; j < 2; j++)
#pragma unroll
            for (int e = 0; e < 4; e++) acc[i][j][e] = 0.0f;
#pragma unroll
    for (int t = 0; t < 2; t++) {
        if (t) __syncthreads();        // all waves done reading before overwrite
        const int k0 = t * 128;
#pragma unroll
        for (int c = 0; c < 4; c++) {  // A: wave stages rows w*16 .. w*16+15
            const int row = w * 16 + c * 4 + rg;
            gload16(X + (size_t)(m0 + row) * 256 + k0 + ((cl ^ (row & 7)) << 3),
                    &As[(w * 16 + c * 4) * 128]);
        }
#pragma unroll
        for (int c = 0; c < 2; c++) {  // B: wave stages rows w*8 .. w*8+7
            const int row = w * 8 + c * 4 + rg;
            gload16(W + (size_t)(n0 + row) * 256 + k0 + ((cl ^ (row & 7)) << 3),
                    &Bs[(w * 8 + c * 4) * 128]);
        }
        asm volatile("s_waitcnt vmcnt(0)" ::: "memory");
        __syncthreads();
#pragma unroll
        for (int kk = 0; kk < 4; kk++) {
            short8 af[2], bf[2];
#pragma unroll
            for (int i = 0; i < 2; i++)
                af[i] = *(const short8*)(&As[(wr * 32 + i * 16 + cl) * 128 + (((kk * 4 + rg) ^ ca) << 3)]);
#pragma unroll
            for (int j = 0; j < 2; j++)
                bf[j] = *(const short8*)(&Bs[(wc * 32 + j * 16 + cl) * 128 + (((kk * 4 + rg) ^ ca) << 3)]);
#pragma unroll
            for (int i = 0; i < 2; i++)
#pragma unroll
                for (int j = 0; j < 2; j++)
                    acc[i][j] = __builtin_amdgcn_mfma_f32_16x16x32_bf16(af[i], bf[j], acc[i][j], 0, 0, 0);
        }
    }
#pragma unroll
    for (int mi = 0; mi < 2; mi++) {
        const int tilebase = m0 + wr * 32 + mi * 16;      // 16-row tile, never straddles s
        const int s = tilebase / R_;
        const int r0 = tilebase - s * R_ + rg * 4;
#pragma unroll
        for (int nj = 0; nj < 2; nj++) {
            if constexpr (EPI == 0) {
                const int cat = blockIdx.y >> 2;
                const int col = ((blockIdx.y & 3) * 64) + wc * 32 + nj * 16 + cl;  // 0..255
                const int h = col >> 5, j = col & 31;
                if (cat == 0) {
#pragma unroll
                    for (int ri = 0; ri < 4; ri++)
                        outq[(((size_t)(s * H_ + h) * R_) + r0 + ri) * HD_ + j] =
                            f2bf(acc[mi][nj][ri] * 0.17677669529663687f);
                } else if (cat == 1) {
#pragma unroll
                    for (int ri = 0; ri < 4; ri++)
                        outk[(((size_t)(s * H_ + h) * R_) + r0 + ri) * HD_ + j] = f2bf(acc[mi][nj][ri]);
                } else if (cat == 2) {
#pragma unroll
                    for (int ri = 0; ri < 4; ri++) {
                        const int r = r0 + ri;
                        const int swz = ((((r >> 3) ^ (j & 7)) << 3) | (r & 7));
                        outvt[(((size_t)(s * H_ + h) * HD_) + j) * R_ + swz] = f2bf(acc[mi][nj][ri]);
                    }
                } else {
                    const float bgv = bg[col];
#pragma unroll
                    for (int ri = 0; ri < 4; ri++) {
                        const float sg = 1.0f / (1.0f + __expf(-(acc[mi][nj][ri] + bgv)));
                        outg[((size_t)(s * R_ + r0 + ri)) * 256 + col] = f2bf(sg);
                    }
                }
            } else {
                const int col = n0 + wc * 32 + nj * 16 + cl;
#pragma unroll
                for (int ri = 0; ri < 4; ri++)
                    outf[((size_t)(s * R_ + r0 + ri)) * 256 + col] = acc[mi][nj][ri];
            }
        }
    }
}

// ------------------------------------------------------------------- attention
// grid (s=128, h=8); 4 waves; each block owns the full (s,h): K[384][32] and
// VT[32][384] (global pre-swizzled: 16B chunk ^= row&7) staged ONCE into LDS
// via a 12-deep reg-staged burst. Each wave processes 6 q-tiles. Swapped QK^T
// (C[k][q] frag, bias+mask as C-init), no max-subtraction (|S|<=~8 by
// construction, validated R5), exp+pack fused per 32-k chunk through a tiny
// per-wave [16][40] dbuf, PV swapped (O^T = mfma(VT,P^T)), 1/sum+gate epilogue.
__global__ __launch_bounds__(256) void attn_kernel(
    const unsigned short* __restrict__ Q, const unsigned short* __restrict__ K,
    const unsigned short* __restrict__ VTX, const unsigned short* __restrict__ G,
    const unsigned short* __restrict__ biasf, const float* __restrict__ mask,
    unsigned short* __restrict__ O)
{
    __shared__ unsigned short Ks[384 * 32];        // 24 KB, row-major [k-row][32]
    __shared__ unsigned short Vs[32 * 384];        // 24 KB, [d-row][384], chunk-swizzled
    __shared__ unsigned short P[4][2][16][40];     // 10 KB, per-wave dbuf
    __shared__ float mk[R_];
    const int tid = threadIdx.x;
    const int lane = tid & 63;
    const int w = tid >> 6;
    const int s = blockIdx.x;
    const int h = blockIdx.y;
    const int rg = lane >> 4;
    const int cl = lane & 15;
    const size_t base = ((size_t)s * H_ + h) * (R_ * HD_);
    // ---- stage K + VT with one 12-deep load burst, then LDS writes ----
    short8 stg[12];
#pragma unroll
    for (int i = 0; i < 6; i++)
        stg[i] = *(const short8*)(K + base + (i * 256 + tid) * 8);
#pragma unroll
    for (int i = 0; i < 6; i++)
        stg[6 + i] = *(const short8*)(VTX + base + (i * 256 + tid) * 8);
    if (tid < 96)
        *(float4*)&mk[tid * 4] = *(const float4*)(mask + (size_t)s * R_ + tid * 4);
#pragma unroll
    for (int i = 0; i < 6; i++) *(short8*)(&Ks[(i * 256 + tid) * 8]) = stg[i];
#pragma unroll
    for (int i = 0; i < 6; i++) *(short8*)(&Vs[(i * 256 + tid) * 8]) = stg[6 + i];
    __syncthreads();
    // ---- per-wave q-tile loop ----
    for (int zz = 0; zz < 6; zz++) {
        const int qtile = zz * 4 + w;
        const int qbase = qtile * 16;
        const short8 qf = *(const short8*)(Q + base + (qbase + cl) * HD_ + rg * 8);
        const unsigned short* bp = biasf + (((size_t)(h * 24 + qtile) * 24) << 8) + (size_t)lane * 4;
        ushort4 bv[24];
#pragma unroll
        for (int ct = 0; ct < 24; ct++) bv[ct] = *(const ushort4*)(bp + ct * 256);
        float sm0 = 0.f, sm1 = 0.f, sm2 = 0.f, sm3 = 0.f;
        f32x4 oa[2][2];
#pragma unroll
        for (int i = 0; i < 2; i++)
#pragma unroll
            for (int p2 = 0; p2 < 2; p2++)
#pragma unroll
                for (int e = 0; e < 4; e++) oa[i][p2][e] = 0.0f;
#pragma unroll
        for (int t = 0; t < 12; t++) {
            // QK^T for the two 16-k halves of this 32-k chunk, fused exp+pack
#pragma unroll
            for (int half = 0; half < 2; half++) {
                const int ct = 2 * t + half;
                const short8 kf = *(const short8*)(&Ks[(ct * 16 + cl) * 32 + rg * 8]);
                const float4 m4 = *(const float4*)(&mk[ct * 16 + rg * 4]);
                f32x4 ini;
                ini[0] = bf2f(bv[ct].x) + m4.x;
                ini[1] = bf2f(bv[ct].y) + m4.y;
                ini[2] = bf2f(bv[ct].z) + m4.z;
                ini[3] = bf2f(bv[ct].w) + m4.w;
                const f32x4 sv = __builtin_amdgcn_mfma_f32_16x16x32_bf16(kf, qf, ini, 0, 0, 0);
                const float e0 = __expf(sv[0]);
                const float e1 = __expf(sv[1]);
                const float e2 = __expf(sv[2]);
                const float e3 = __expf(sv[3]);
                sm0 += e0; sm1 += e1; sm2 += e2; sm3 += e3;
                uint2 pk;
                pk.x = (unsigned)f2bf(e0) | ((unsigned)f2bf(e1) << 16);
                pk.y = (unsigned)f2bf(e2) | ((unsigned)f2bf(e3) << 16);
                *(uint2*)(&P[w][t & 1][cl][half * 16 + rg * 4]) = pk;
            }
            // same-wave LDS write->read fence
            asm volatile("s_waitcnt lgkmcnt(0)" ::: "memory");
            const short8 pf = *(const short8*)(&P[w][t & 1][cl][rg * 8]);
#pragma unroll
            for (int sub = 0; sub < 2; sub++) {
                const int row = sub * 16 + cl;
                const short8 vf = *(const short8*)(&Vs[row * 384 + (((t * 4 + rg) ^ (row & 7)) << 3)]);
                oa[sub][t & 1] = __builtin_amdgcn_mfma_f32_16x16x32_bf16(vf, pf, oa[sub][t & 1], 0, 0, 0);
            }
        }
        float sum = (sm0 + sm1) + (sm2 + sm3);
        sum += __shfl_xor(sum, 16);
        sum += __shfl_xor(sum, 32);
        const float inv = 1.0f / sum;
        // epilogue: normalize, gate, store. lane holds O^T[d=sub*16+rg*4+ri][q=qbase+cl]
        const size_t orow = (size_t)(s * R_ + qbase + cl) * 256 + h * HD_;
#pragma unroll
        for (int sub = 0; sub < 2; sub++) {
            const ushort4 gv = *(const ushort4*)(G + orow + sub * 16 + rg * 4);
            ushort4 ov;
            ov.x = f2bf((oa[sub][0][0] + oa[sub][1][0]) * inv * bf2f(gv.x));
            ov.y = f2bf((oa[sub][0][1] + oa[sub][1][1]) * inv * bf2f(gv.y));
            ov.z = f2bf((oa[sub][0][2] + oa[sub][1][2]) * inv * bf2f(gv.z));
            ov.w = f2bf((oa[sub][0][3] + oa[sub][1][3]) * inv * bf2f(gv.w));
            *(ushort4*)(O + orow + sub * 16 + rg * 4) = ov;
        }
    }
}

// ------------------------------------------------------------------------ host
extern "C" void kernel_launch(void* const* d_in, const int* in_sizes, int n_in,
                              void* d_out, int out_size, void* d_ws, size_t ws_size,
                              hipStream_t stream)
{
    const float* m      = (const float*)d_in[0];
    const float* z      = (const float*)d_in[1];
    const float* mask   = (const float*)d_in[2];
    const float* ln_m_w = (const float*)d_in[3];
    const float* ln_m_b = (const float*)d_in[4];
    const float* ln_z_w = (const float*)d_in[5];
    const float* ln_z_b = (const float*)d_in[6];
    const float* Wz     = (const float*)d_in[7];
    const float* Wq     = (const float*)d_in[8];
    const float* Wk     = (const float*)d_in[9];
    const float* Wv     = (const float*)d_in[10];
    const float* Wg     = (const float*)d_in[11];
    const float* bg     = (const float*)d_in[12];
    const float* Wo     = (const float*)d_in[13];
    float* out = (float*)d_out;
    char* ws = (char*)d_ws;

    // ws layout (bytes)
    unsigned short* wbias = (unsigned short*)(ws);                         //  2,359,296
    unsigned short* wmn   = (unsigned short*)(ws + 2359296);               // 25,165,824 (reused as attn O)
    unsigned short* wq    = (unsigned short*)(ws + 27525120);              // 25,165,824
    unsigned short* wk    = (unsigned short*)(ws + 52690944);              // 25,165,824
    unsigned short* wvt   = (unsigned short*)(ws + 77856768);              // 25,165,824
    unsigned short* wg    = (unsigned short*)(ws + 103022592);             // 25,165,824
    unsigned short* wcat  = (unsigned short*)(ws + 128188416);             //    524,288
    unsigned short* wwo   = (unsigned short*)(ws + 128712704);             //    131,072
    // bias precompute tables live in the wq region (dead until gemm<0> runs)
    float* Af  = (float*)wq;            // 8x128 f32 = 4 KB
    float* c12 = Af + 1024;             // 16 f32

    wconv_kernel<<<1024, 256, 0, stream>>>(Wq, Wk, Wv, Wg, Wo, wcat, wwo);
    prep_kernel<<<1, 128, 0, stream>>>(ln_z_w, ln_z_b, Wz, Af, c12);
    bias_kernel<<<4608, 256, 0, stream>>>(z, Af, c12, wbias);
    lnm_kernel<<<12288, 256, 0, stream>>>(m, ln_m_w, ln_m_b, wmn);
    gemm_kernel<0><<<dim3(384, 16), 512, 0, stream>>>(wmn, wcat, bg, wq, wk, wvt, wg, nullptr);
    attn_kernel<<<dim3(128, 8), 256, 0, stream>>>(wq, wk, wvt, wg, wbias, mask, wmn);
    gemm_kernel<1><<<dim3(384, 4), 512, 0, stream>>>(wmn, wwo, nullptr, nullptr, nullptr, nullptr, nullptr, out);
}